// Round 1
// baseline (3120.834 us; speedup 1.0000x reference)
//
#include <hip/hip_runtime.h>

#define N_NODES 50000
#define N_EDGES 800000

// ---------------------------------------------------------------------------
// init agg = x (float4 copy; ws is poisoned before every launch)
// ---------------------------------------------------------------------------
__global__ void copy4_kernel(const float4* __restrict__ s, float4* __restrict__ d, int n4) {
    int i = blockIdx.x * blockDim.x + threadIdx.x;
    if (i < n4) d[i] = s[i];
}

// ---------------------------------------------------------------------------
// agg[dst[e]] += x[src[e]]  (edge-parallel, 32 lanes per edge, float4 gather)
// ---------------------------------------------------------------------------
__global__ void scatter_add_kernel(const float* __restrict__ x,
                                   const int* __restrict__ srcv,
                                   const int* __restrict__ dstv,
                                   float* __restrict__ agg) {
    int t = blockIdx.x * blockDim.x + threadIdx.x;
    int e = t >> 5;
    if (e >= N_EDGES) return;
    int c = (t & 31) << 2;                       // float offset within the 128-d row
    int s = srcv[e];
    int d = dstv[e];
    const float4 v = *reinterpret_cast<const float4*>(x + (size_t)s * 128 + c);
    float* p = agg + (size_t)d * 128 + c;
    atomicAdd(p + 0, v.x);
    atomicAdd(p + 1, v.y);
    atomicAdd(p + 2, v.z);
    atomicAdd(p + 3, v.w);
}

// ---------------------------------------------------------------------------
// Y[M,N] = act(X[M,K] @ W[K,N] + b)   — TM rows per block staged in LDS,
// one output column per thread; W reads coalesced across the block and
// L2-resident (<=256 KB), reused by all 6250 blocks.
// ---------------------------------------------------------------------------
template <int K, int N, int BLOCK, int TM, bool RELU>
__global__ __launch_bounds__(BLOCK) void rowgemm_kernel(
    const float* __restrict__ X, const float* __restrict__ W,
    const float* __restrict__ bias, float* __restrict__ Y, int M) {
    __shared__ float xs[TM][K];
    const int row0 = blockIdx.x * TM;
    const int j = threadIdx.x;

    for (int idx = threadIdx.x; idx < TM * K; idx += BLOCK) {
        int r = idx / K, k = idx - r * K;
        int row = row0 + r;
        xs[r][k] = (row < M) ? X[(size_t)row * K + k] : 0.f;
    }
    __syncthreads();

    if (j < N) {
        float acc[TM];
#pragma unroll
        for (int r = 0; r < TM; ++r) acc[r] = 0.f;
        const float* Wj = W + j;
        for (int k = 0; k < K; ++k) {
            float w = Wj[(size_t)k * N];
#pragma unroll
            for (int r = 0; r < TM; ++r) acc[r] = fmaf(xs[r][k], w, acc[r]);
        }
        float bj = bias[j];
#pragma unroll
        for (int r = 0; r < TM; ++r) {
            int row = row0 + r;
            if (row < M) {
                float v = acc[r] + bj;
                if (RELU) v = fmaxf(v, 0.f);
                Y[(size_t)row * N + j] = v;
            }
        }
    }
}

// ---------------------------------------------------------------------------
extern "C" void kernel_launch(void* const* d_in, const int* in_sizes, int n_in,
                              void* d_out, int out_size, void* d_ws, size_t ws_size,
                              hipStream_t stream) {
    const float* x   = (const float*)d_in[0];
    const int*   ei  = (const int*)d_in[1];
    const float* W11 = (const float*)d_in[2];
    const float* b11 = (const float*)d_in[3];
    const float* W12 = (const float*)d_in[4];
    const float* b12 = (const float*)d_in[5];
    const float* W21 = (const float*)d_in[6];
    const float* b21 = (const float*)d_in[7];
    const float* W22 = (const float*)d_in[8];
    const float* b22 = (const float*)d_in[9];
    const float* Wfc = (const float*)d_in[10];
    const float* bfc = (const float*)d_in[11];
    float* out = (float*)d_out;

    const int* srcv = ei;             // edge_index[0, :]
    const int* dstv = ei + N_EDGES;   // edge_index[1, :]

    float* agg = (float*)d_ws;                         // 50000*128 f32 = 25.6 MB
    float* t   = agg + (size_t)N_NODES * 128;          // 50000*256 f32 = 51.2 MB
    float* h   = t   + (size_t)N_NODES * 256;          // 50000*128 f32 = 25.6 MB

    const int n4 = N_NODES * 128 / 4;                  // 1.6M float4
    dim3 cblk(256), cgrid((n4 + 255) / 256);
    dim3 sblk(256), sgrid((N_EDGES * 32 + 255) / 256); // 100000 blocks

    // ---- layer 1: aggregate (agg = x + scatter(x)) ----
    copy4_kernel<<<cgrid, cblk, 0, stream>>>((const float4*)x, (float4*)agg, n4);
    scatter_add_kernel<<<sgrid, sblk, 0, stream>>>(x, srcv, dstv, agg);
    // ---- MLP 1: t = relu(agg@W11+b11); h = relu(t@W12+b12) ----
    rowgemm_kernel<128, 256, 256, 8, true><<<6250, 256, 0, stream>>>(agg, W11, b11, t, N_NODES);
    rowgemm_kernel<256, 128, 128, 8, true><<<6250, 128, 0, stream>>>(t, W12, b12, h, N_NODES);
    // ---- layer 2: aggregate (agg = h + scatter(h)) ----
    copy4_kernel<<<cgrid, cblk, 0, stream>>>((const float4*)h, (float4*)agg, n4);
    scatter_add_kernel<<<sgrid, sblk, 0, stream>>>(h, srcv, dstv, agg);
    // ---- MLP 2 ----
    rowgemm_kernel<128, 256, 256, 8, true><<<6250, 256, 0, stream>>>(agg, W21, b21, t, N_NODES);
    rowgemm_kernel<256, 128, 128, 8, true><<<6250, 128, 0, stream>>>(t, W22, b22, h, N_NODES);
    // ---- classifier: out = h@Wfc + bfc ----
    rowgemm_kernel<128, 40, 64, 8, false><<<6250, 64, 0, stream>>>(h, Wfc, bfc, out, N_NODES);
}

// Round 2
// 716.304 us; speedup vs baseline: 4.3569x; 4.3569x over previous
//
#include <hip/hip_runtime.h>

#define N_NODES 50000
#define N_EDGES 800000

// ---------------------------------------------------------------------------
// CSR build: zero -> histogram(dst) -> scan -> permute(src by dst)
// ---------------------------------------------------------------------------
__global__ void zero_kernel(int* __restrict__ p, int n) {
    int i = blockIdx.x * blockDim.x + threadIdx.x;
    if (i < n) p[i] = 0;
}

__global__ void hist_kernel(const int* __restrict__ dstv, int* __restrict__ deg) {
    int e = blockIdx.x * blockDim.x + threadIdx.x;
    if (e < N_EDGES) atomicAdd(&deg[dstv[e]], 1);
}

// single-block exclusive scan of deg[0..N) -> row_ptr, cursor (mutable copy)
__global__ __launch_bounds__(1024) void scan_kernel(const int* __restrict__ deg,
                                                    int* __restrict__ row_ptr,
                                                    int* __restrict__ cursor) {
    __shared__ int part[1024];
    const int chunk = (N_NODES + 1023) / 1024;  // 49
    int t = threadIdx.x;
    int b = t * chunk;
    int e = min(b + chunk, N_NODES);
    int s = 0;
    for (int i = b; i < e; ++i) s += deg[i];
    part[t] = s;
    __syncthreads();
    for (int off = 1; off < 1024; off <<= 1) {
        int v = (t >= off) ? part[t - off] : 0;
        __syncthreads();
        part[t] += v;
        __syncthreads();
    }
    int run = (t == 0) ? 0 : part[t - 1];
    for (int i = b; i < e; ++i) {
        row_ptr[i] = run;
        cursor[i] = run;
        run += deg[i];
    }
    if (t == 1023) row_ptr[N_NODES] = run;  // == N_EDGES
}

__global__ void permute_kernel(const int* __restrict__ srcv, const int* __restrict__ dstv,
                               int* __restrict__ cursor, int* __restrict__ e_src) {
    int e = blockIdx.x * blockDim.x + threadIdx.x;
    if (e < N_EDGES) {
        int pos = atomicAdd(&cursor[dstv[e]], 1);
        e_src[pos] = srcv[e];
    }
}

// ---------------------------------------------------------------------------
// agg[i] = x[i] + sum_{e in CSR row i} x[e_src[e]]   — one wave per node,
// float2 per lane (64 lanes x 2 = 128), no atomics, one write per element.
// ---------------------------------------------------------------------------
__global__ __launch_bounds__(256) void gin_aggregate_csr(
    const float* __restrict__ x, const int* __restrict__ row_ptr,
    const int* __restrict__ e_src, float* __restrict__ agg) {
    int node = (blockIdx.x * 256 + threadIdx.x) >> 6;
    if (node >= N_NODES) return;
    int lane = threadIdx.x & 63;
    const size_t off = (size_t)lane * 2;
    const int beg = row_ptr[node], end = row_ptr[node + 1];
    float2 acc = *reinterpret_cast<const float2*>(x + (size_t)node * 128 + off);
    int e = beg;
    for (; e + 1 < end; e += 2) {
        int s0 = e_src[e], s1 = e_src[e + 1];
        float2 v0 = *reinterpret_cast<const float2*>(x + (size_t)s0 * 128 + off);
        float2 v1 = *reinterpret_cast<const float2*>(x + (size_t)s1 * 128 + off);
        acc.x += v0.x + v1.x;
        acc.y += v0.y + v1.y;
    }
    if (e < end) {
        int s = e_src[e];
        float2 v = *reinterpret_cast<const float2*>(x + (size_t)s * 128 + off);
        acc.x += v.x;
        acc.y += v.y;
    }
    *reinterpret_cast<float2*>(agg + (size_t)node * 128 + off) = acc;
}

// ---------------------------------------------------------------------------
// Y[M,N] = act(X[M,K] @ W[K,N] + b) — TM rows staged in LDS, col per thread
// ---------------------------------------------------------------------------
template <int K, int N, int BLOCK, int TM, bool RELU>
__global__ __launch_bounds__(BLOCK) void rowgemm_kernel(
    const float* __restrict__ X, const float* __restrict__ W,
    const float* __restrict__ bias, float* __restrict__ Y, int M) {
    __shared__ float xs[TM][K];
    const int row0 = blockIdx.x * TM;
    const int j = threadIdx.x;

    for (int idx = threadIdx.x; idx < TM * K; idx += BLOCK) {
        int r = idx / K, k = idx - r * K;
        int row = row0 + r;
        xs[r][k] = (row < M) ? X[(size_t)row * K + k] : 0.f;
    }
    __syncthreads();

    if (j < N) {
        float acc[TM];
#pragma unroll
        for (int r = 0; r < TM; ++r) acc[r] = 0.f;
        const float* Wj = W + j;
        for (int k = 0; k < K; ++k) {
            float w = Wj[(size_t)k * N];
#pragma unroll
            for (int r = 0; r < TM; ++r) acc[r] = fmaf(xs[r][k], w, acc[r]);
        }
        float bj = bias[j];
#pragma unroll
        for (int r = 0; r < TM; ++r) {
            int row = row0 + r;
            if (row < M) {
                float v = acc[r] + bj;
                if (RELU) v = fmaxf(v, 0.f);
                Y[(size_t)row * N + j] = v;
            }
        }
    }
}

// ---------------------------------------------------------------------------
extern "C" void kernel_launch(void* const* d_in, const int* in_sizes, int n_in,
                              void* d_out, int out_size, void* d_ws, size_t ws_size,
                              hipStream_t stream) {
    const float* x   = (const float*)d_in[0];
    const int*   ei  = (const int*)d_in[1];
    const float* W11 = (const float*)d_in[2];
    const float* b11 = (const float*)d_in[3];
    const float* W12 = (const float*)d_in[4];
    const float* b12 = (const float*)d_in[5];
    const float* W21 = (const float*)d_in[6];
    const float* b21 = (const float*)d_in[7];
    const float* W22 = (const float*)d_in[8];
    const float* b22 = (const float*)d_in[9];
    const float* Wfc = (const float*)d_in[10];
    const float* bfc = (const float*)d_in[11];
    float* out = (float*)d_out;

    const int* srcv = ei;             // edge_index[0, :]
    const int* dstv = ei + N_EDGES;   // edge_index[1, :]

    float* agg = (float*)d_ws;                         // 50000*128 f32
    float* t   = agg + (size_t)N_NODES * 128;          // 50000*256 f32
    float* h   = t   + (size_t)N_NODES * 256;          // 50000*128 f32
    int*   deg     = (int*)(h + (size_t)N_NODES * 128);
    int*   row_ptr = deg + N_NODES;                    // N+1
    int*   cursor  = row_ptr + N_NODES + 1;
    int*   e_src   = cursor + N_NODES;                 // E ints

    // ---- CSR build (once per call; reused by both layers) ----
    zero_kernel<<<(N_NODES + 255) / 256, 256, 0, stream>>>(deg, N_NODES);
    hist_kernel<<<(N_EDGES + 255) / 256, 256, 0, stream>>>(dstv, deg);
    scan_kernel<<<1, 1024, 0, stream>>>(deg, row_ptr, cursor);
    permute_kernel<<<(N_EDGES + 255) / 256, 256, 0, stream>>>(srcv, dstv, cursor, e_src);

    const int agg_blocks = (N_NODES * 64 + 255) / 256;  // one wave per node

    // ---- layer 1 ----
    gin_aggregate_csr<<<agg_blocks, 256, 0, stream>>>(x, row_ptr, e_src, agg);
    rowgemm_kernel<128, 256, 256, 8, true><<<6250, 256, 0, stream>>>(agg, W11, b11, t, N_NODES);
    rowgemm_kernel<256, 128, 128, 8, true><<<6250, 128, 0, stream>>>(t, W12, b12, h, N_NODES);
    // ---- layer 2 ----
    gin_aggregate_csr<<<agg_blocks, 256, 0, stream>>>(h, row_ptr, e_src, agg);
    rowgemm_kernel<128, 256, 256, 8, true><<<6250, 256, 0, stream>>>(agg, W21, b21, t, N_NODES);
    rowgemm_kernel<256, 128, 128, 8, true><<<6250, 128, 0, stream>>>(t, W22, b22, h, N_NODES);
    // ---- classifier ----
    rowgemm_kernel<128, 40, 64, 8, false><<<6250, 64, 0, stream>>>(h, Wfc, bfc, out, N_NODES);
}

// Round 3
// 412.725 us; speedup vs baseline: 7.5615x; 1.7355x over previous
//
#include <hip/hip_runtime.h>

#define N_NODES 50000
#define N_EDGES 800000
#define NB256   ((N_NODES + 255) / 256)   // 196 blocks for node-sized arrays

typedef __attribute__((ext_vector_type(8))) short short8;
typedef __attribute__((ext_vector_type(4))) float floatx4;

__device__ __forceinline__ float b2f(unsigned short u) {
    union { unsigned int i; float f; } v;
    v.i = ((unsigned int)u) << 16;
    return v.f;
}
__device__ __forceinline__ unsigned short f2b(float f) {  // round-nearest-even
    union { float f; unsigned int i; } v;
    v.f = f;
    unsigned int r = v.i + 0x7FFFu + ((v.i >> 16) & 1u);
    return (unsigned short)(r >> 16);
}

// ---------------------------------------------------------------------------
// CSR build
// ---------------------------------------------------------------------------
__global__ void zero_kernel(int* __restrict__ p, int n) {
    int i = blockIdx.x * blockDim.x + threadIdx.x;
    if (i < n) p[i] = 0;
}

__global__ void hist_kernel(const int* __restrict__ dstv, int* __restrict__ deg) {
    int e = blockIdx.x * blockDim.x + threadIdx.x;
    if (e < N_EDGES) atomicAdd(&deg[dstv[e]], 1);
}

// block-level inclusive scans of deg -> incl, block totals -> sums
__global__ __launch_bounds__(256) void scan_part(const int* __restrict__ deg,
                                                 int* __restrict__ incl,
                                                 int* __restrict__ sums) {
    __shared__ int sh[256];
    int t = threadIdx.x;
    int i = blockIdx.x * 256 + t;
    int v = (i < N_NODES) ? deg[i] : 0;
    sh[t] = v;
    __syncthreads();
    for (int off = 1; off < 256; off <<= 1) {
        int u = (t >= off) ? sh[t - off] : 0;
        __syncthreads();
        sh[t] += u;
        __syncthreads();
    }
    if (i < N_NODES) incl[i] = sh[t];
    if (t == 255) sums[blockIdx.x] = sh[255];
}

// exclusive scan of the 196 block sums
__global__ __launch_bounds__(256) void scan_tops(const int* __restrict__ sums,
                                                 int* __restrict__ tops) {
    __shared__ int sh[256];
    int t = threadIdx.x;
    int v = (t < NB256) ? sums[t] : 0;
    sh[t] = v;
    __syncthreads();
    for (int off = 1; off < 256; off <<= 1) {
        int u = (t >= off) ? sh[t - off] : 0;
        __syncthreads();
        sh[t] += u;
        __syncthreads();
    }
    if (t < NB256) tops[t] = sh[t] - v;
}

__global__ void scan_final(const int* __restrict__ deg, const int* __restrict__ incl,
                           const int* __restrict__ tops, int* __restrict__ row_ptr,
                           int* __restrict__ cursor) {
    int i = blockIdx.x * blockDim.x + threadIdx.x;
    if (i < N_NODES) {
        int rp = tops[i >> 8] + incl[i] - deg[i];
        row_ptr[i] = rp;
        cursor[i] = rp;
    }
    if (i == 0) row_ptr[N_NODES] = N_EDGES;
}

__global__ void permute_kernel(const int* __restrict__ srcv, const int* __restrict__ dstv,
                               int* __restrict__ cursor, int* __restrict__ e_src) {
    int e = blockIdx.x * blockDim.x + threadIdx.x;
    if (e < N_EDGES) {
        int pos = atomicAdd(&cursor[dstv[e]], 1);
        e_src[pos] = srcv[e];
    }
}

// ---------------------------------------------------------------------------
// weight prep: W[K][N] fp32 -> Wt[N][K] bf16
// ---------------------------------------------------------------------------
__global__ void wconv_kernel(const float* __restrict__ W, unsigned short* __restrict__ Wt,
                             int K, int N) {
    int idx = blockIdx.x * blockDim.x + threadIdx.x;
    if (idx < K * N) {
        int k = idx / N, n = idx - k * N;
        Wt[n * K + k] = f2b(W[idx]);
    }
}

// ---------------------------------------------------------------------------
// aggregate: agg[i] = x[i] + sum_{e in row i} x[e_src[e]]  (one wave per node)
// fp32 input variant (layer 1)
// ---------------------------------------------------------------------------
__global__ __launch_bounds__(256) void agg_f32(const float* __restrict__ x,
                                               const int* __restrict__ row_ptr,
                                               const int* __restrict__ e_src,
                                               unsigned short* __restrict__ agg) {
    int node = (blockIdx.x * 256 + threadIdx.x) >> 6;
    if (node >= N_NODES) return;
    int lane = threadIdx.x & 63;
    const size_t off = (size_t)lane * 2;
    const int beg = row_ptr[node], end = row_ptr[node + 1];
    float2 acc = *reinterpret_cast<const float2*>(x + (size_t)node * 128 + off);
    int e = beg;
    for (; e + 1 < end; e += 2) {
        int s0 = e_src[e], s1 = e_src[e + 1];
        float2 v0 = *reinterpret_cast<const float2*>(x + (size_t)s0 * 128 + off);
        float2 v1 = *reinterpret_cast<const float2*>(x + (size_t)s1 * 128 + off);
        acc.x += v0.x + v1.x;
        acc.y += v0.y + v1.y;
    }
    if (e < end) {
        int s = e_src[e];
        float2 v = *reinterpret_cast<const float2*>(x + (size_t)s * 128 + off);
        acc.x += v.x;
        acc.y += v.y;
    }
    unsigned short* p = agg + (size_t)node * 128 + off;
    p[0] = f2b(acc.x);
    p[1] = f2b(acc.y);
}

// bf16 input variant (layer 2)
__global__ __launch_bounds__(256) void agg_bf16(const unsigned short* __restrict__ x,
                                                const int* __restrict__ row_ptr,
                                                const int* __restrict__ e_src,
                                                unsigned short* __restrict__ agg) {
    int node = (blockIdx.x * 256 + threadIdx.x) >> 6;
    if (node >= N_NODES) return;
    int lane = threadIdx.x & 63;
    const size_t off = (size_t)lane * 2;
    const int beg = row_ptr[node], end = row_ptr[node + 1];
    ushort2 u = *reinterpret_cast<const ushort2*>(x + (size_t)node * 128 + off);
    float ax = b2f(u.x), ay = b2f(u.y);
    int e = beg;
    for (; e + 1 < end; e += 2) {
        int s0 = e_src[e], s1 = e_src[e + 1];
        ushort2 u0 = *reinterpret_cast<const ushort2*>(x + (size_t)s0 * 128 + off);
        ushort2 u1 = *reinterpret_cast<const ushort2*>(x + (size_t)s1 * 128 + off);
        ax += b2f(u0.x) + b2f(u1.x);
        ay += b2f(u0.y) + b2f(u1.y);
    }
    if (e < end) {
        int s = e_src[e];
        ushort2 u0 = *reinterpret_cast<const ushort2*>(x + (size_t)s * 128 + off);
        ax += b2f(u0.x);
        ay += b2f(u0.y);
    }
    unsigned short* p = agg + (size_t)node * 128 + off;
    p[0] = f2b(ax);
    p[1] = f2b(ay);
}

// ---------------------------------------------------------------------------
// MFMA GEMM: Y[M,N] = act(X[M,K]@W[K,N]+b), X bf16 row-major, Wt bf16 [N][K],
// Y bf16. 128x128 block tile, 4 waves 2x2, 16x16x32 mfma, fp32 accumulate.
// ---------------------------------------------------------------------------
#define LDST 136  // 128 + 8 bf16 pad: 16B-aligned rows, 2-way bank alias only

template <int K, bool RELU>
__global__ __launch_bounds__(256, 2) void mfma_gemm(
    const unsigned short* __restrict__ X, const unsigned short* __restrict__ Wt,
    const float* __restrict__ bias, unsigned short* __restrict__ Y, int M, int N) {
    __shared__ unsigned short A_lds[128 * LDST];
    __shared__ unsigned short B_lds[128 * LDST];

    const int tid = threadIdx.x;
    const int m0 = blockIdx.x * 128;
    const int n0 = blockIdx.y * 128;
    const int lane = tid & 63, wave = tid >> 6;
    const int wm = (wave >> 1) * 64, wn = (wave & 1) * 64;
    const int qm = lane & 15, quad = lane >> 4;

    floatx4 acc[4][4];
#pragma unroll
    for (int mt = 0; mt < 4; ++mt)
#pragma unroll
        for (int nt = 0; nt < 4; ++nt) acc[mt][nt] = {0.f, 0.f, 0.f, 0.f};

    for (int kc = 0; kc < K; kc += 128) {
        if (kc) __syncthreads();
        // stage A: rows m0..+127, k kc..+127 (zero-fill past M)
#pragma unroll
        for (int i = 0; i < 8; ++i) {
            int idx = i * 256 + tid;            // 0..2047
            int r = idx >> 4;                   // row 0..127
            int c8 = (idx & 15) << 3;           // k-octet
            uint4 v = {0, 0, 0, 0};
            int row = m0 + r;
            if (row < M) v = *reinterpret_cast<const uint4*>(X + (size_t)row * K + kc + c8);
            *reinterpret_cast<uint4*>(&A_lds[r * LDST + c8]) = v;
        }
        // stage B (Wt is [N][K], rows n0..+127 all valid)
#pragma unroll
        for (int i = 0; i < 8; ++i) {
            int idx = i * 256 + tid;
            int r = idx >> 4;
            int c8 = (idx & 15) << 3;
            uint4 v = *reinterpret_cast<const uint4*>(Wt + (size_t)(n0 + r) * K + kc + c8);
            *reinterpret_cast<uint4*>(&B_lds[r * LDST + c8]) = v;
        }
        __syncthreads();

#pragma unroll
        for (int ks = 0; ks < 4; ++ks) {
            short8 a[4], b[4];
            const int kb = ks * 32 + quad * 8;
#pragma unroll
            for (int mt = 0; mt < 4; ++mt)
                a[mt] = *reinterpret_cast<const short8*>(&A_lds[(wm + mt * 16 + qm) * LDST + kb]);
#pragma unroll
            for (int nt = 0; nt < 4; ++nt)
                b[nt] = *reinterpret_cast<const short8*>(&B_lds[(wn + nt * 16 + qm) * LDST + kb]);
#pragma unroll
            for (int mt = 0; mt < 4; ++mt)
#pragma unroll
                for (int nt = 0; nt < 4; ++nt)
                    acc[mt][nt] = __builtin_amdgcn_mfma_f32_16x16x32_bf16(
                        a[mt], b[nt], acc[mt][nt], 0, 0, 0);
        }
    }

    // epilogue: C/D layout col=lane&15, row=quad*4+reg
#pragma unroll
    for (int nt = 0; nt < 4; ++nt) {
        int col = n0 + wn + nt * 16 + qm;
        float bj = bias[col];
#pragma unroll
        for (int mt = 0; mt < 4; ++mt) {
#pragma unroll
            for (int r = 0; r < 4; ++r) {
                int row = m0 + wm + mt * 16 + quad * 4 + r;
                if (row < M) {
                    float v = acc[mt][nt][r] + bj;
                    if (RELU) v = fmaxf(v, 0.f);
                    Y[(size_t)row * N + col] = f2b(v);
                }
            }
        }
    }
}

// ---------------------------------------------------------------------------
// classifier: out[M,40] = h[M,128] @ Wfc[128,40] + bfc  — one row per thread,
// W broadcast from LDS
// ---------------------------------------------------------------------------
__global__ __launch_bounds__(256) void classifier_kernel(
    const unsigned short* __restrict__ h, const float* __restrict__ Wfc,
    const float* __restrict__ bfc, float* __restrict__ out) {
    __shared__ float Ws[128 * 40];
    __shared__ float bs[40];
    for (int i = threadIdx.x; i < 128 * 40; i += 256) Ws[i] = Wfc[i];
    if (threadIdx.x < 40) bs[threadIdx.x] = bfc[threadIdx.x];
    __syncthreads();

    int row = blockIdx.x * 256 + threadIdx.x;
    if (row >= N_NODES) return;
    float acc[40];
#pragma unroll
    for (int j = 0; j < 40; ++j) acc[j] = bs[j];
    const unsigned short* hr = h + (size_t)row * 128;
    for (int k8 = 0; k8 < 128; k8 += 8) {
        ushort4 u0 = *reinterpret_cast<const ushort4*>(hr + k8);
        ushort4 u1 = *reinterpret_cast<const ushort4*>(hr + k8 + 4);
        float xv[8] = {b2f(u0.x), b2f(u0.y), b2f(u0.z), b2f(u0.w),
                       b2f(u1.x), b2f(u1.y), b2f(u1.z), b2f(u1.w)};
#pragma unroll
        for (int kk = 0; kk < 8; ++kk)
#pragma unroll
            for (int j = 0; j < 40; ++j)
                acc[j] = fmaf(xv[kk], Ws[(k8 + kk) * 40 + j], acc[j]);
    }
    float* orow = out + (size_t)row * 40;
#pragma unroll
    for (int j = 0; j < 40; ++j) orow[j] = acc[j];
}

// ---------------------------------------------------------------------------
extern "C" void kernel_launch(void* const* d_in, const int* in_sizes, int n_in,
                              void* d_out, int out_size, void* d_ws, size_t ws_size,
                              hipStream_t stream) {
    const float* x   = (const float*)d_in[0];
    const int*   ei  = (const int*)d_in[1];
    const float* W11 = (const float*)d_in[2];
    const float* b11 = (const float*)d_in[3];
    const float* W12 = (const float*)d_in[4];
    const float* b12 = (const float*)d_in[5];
    const float* W21 = (const float*)d_in[6];
    const float* b21 = (const float*)d_in[7];
    const float* W22 = (const float*)d_in[8];
    const float* b22 = (const float*)d_in[9];
    const float* Wfc = (const float*)d_in[10];
    const float* bfc = (const float*)d_in[11];
    float* out = (float*)d_out;

    const int* srcv = ei;
    const int* dstv = ei + N_EDGES;

    // workspace layout (all 16B aligned)
    unsigned short* agg  = (unsigned short*)d_ws;               // 50000*128 bf16
    unsigned short* t    = agg + (size_t)N_NODES * 128;         // 50000*256 bf16
    unsigned short* h    = t   + (size_t)N_NODES * 256;         // 50000*128 bf16
    unsigned short* Wt11 = h   + (size_t)N_NODES * 128;         // 256*128
    unsigned short* Wt12 = Wt11 + 256 * 128;                    // 128*256
    unsigned short* Wt21 = Wt12 + 256 * 128;
    unsigned short* Wt22 = Wt21 + 256 * 128;
    int* deg     = (int*)(Wt22 + 256 * 128);
    int* row_ptr = deg + N_NODES;                               // N+1
    int* cursor  = row_ptr + N_NODES + 4;
    int* e_src   = cursor + N_NODES;
    int* incl    = e_src + N_EDGES;
    int* sums    = incl + NB256 * 256;
    int* tops    = sums + 256;

    // ---- weight prep ----
    wconv_kernel<<<128, 256, 0, stream>>>(W11, Wt11, 128, 256);
    wconv_kernel<<<128, 256, 0, stream>>>(W12, Wt12, 256, 128);
    wconv_kernel<<<128, 256, 0, stream>>>(W21, Wt21, 128, 256);
    wconv_kernel<<<128, 256, 0, stream>>>(W22, Wt22, 256, 128);

    // ---- CSR build ----
    zero_kernel<<<NB256, 256, 0, stream>>>(deg, N_NODES);
    hist_kernel<<<(N_EDGES + 255) / 256, 256, 0, stream>>>(dstv, deg);
    scan_part<<<NB256, 256, 0, stream>>>(deg, incl, sums);
    scan_tops<<<1, 256, 0, stream>>>(sums, tops);
    scan_final<<<NB256, 256, 0, stream>>>(deg, incl, tops, row_ptr, cursor);
    permute_kernel<<<(N_EDGES + 255) / 256, 256, 0, stream>>>(srcv, dstv, cursor, e_src);

    const int agg_blocks = N_NODES * 64 / 256;  // 12500, one wave per node

    // ---- layer 1 ----
    agg_f32<<<agg_blocks, 256, 0, stream>>>(x, row_ptr, e_src, agg);
    mfma_gemm<128, true><<<dim3(391, 2), 256, 0, stream>>>(agg, Wt11, b11, t, N_NODES, 256);
    mfma_gemm<256, true><<<dim3(391, 1), 256, 0, stream>>>(t, Wt12, b12, h, N_NODES, 128);
    // ---- layer 2 ----
    agg_bf16<<<agg_blocks, 256, 0, stream>>>(h, row_ptr, e_src, agg);
    mfma_gemm<128, true><<<dim3(391, 2), 256, 0, stream>>>(agg, Wt21, b21, t, N_NODES, 256);
    mfma_gemm<256, true><<<dim3(391, 1), 256, 0, stream>>>(t, Wt22, b22, h, N_NODES, 128);
    // ---- classifier ----
    classifier_kernel<<<NB256, 256, 0, stream>>>(h, Wfc, bfc, out);
}

// Round 4
// 370.575 us; speedup vs baseline: 8.4216x; 1.1137x over previous
//
#include <hip/hip_runtime.h>

#define N_NODES 50000
#define N_EDGES 800000
#define NB256   ((N_NODES + 255) / 256)   // 196 blocks for node-sized arrays

typedef __attribute__((ext_vector_type(8))) short short8;
typedef __attribute__((ext_vector_type(4))) float floatx4;

__device__ __forceinline__ float b2f(unsigned short u) {
    union { unsigned int i; float f; } v;
    v.i = ((unsigned int)u) << 16;
    return v.f;
}
__device__ __forceinline__ unsigned short f2b(float f) {  // round-nearest-even
    union { float f; unsigned int i; } v;
    v.f = f;
    unsigned int r = v.i + 0x7FFFu + ((v.i >> 16) & 1u);
    return (unsigned short)(r >> 16);
}

// ---------------------------------------------------------------------------
// CSR build
// ---------------------------------------------------------------------------
__global__ void zero_kernel(int* __restrict__ p, int n) {
    int i = blockIdx.x * blockDim.x + threadIdx.x;
    if (i < n) p[i] = 0;
}

__global__ void hist_kernel(const int* __restrict__ dstv, int* __restrict__ deg) {
    int e = blockIdx.x * blockDim.x + threadIdx.x;
    if (e < N_EDGES) atomicAdd(&deg[dstv[e]], 1);
}

__global__ __launch_bounds__(256) void scan_part(const int* __restrict__ deg,
                                                 int* __restrict__ incl,
                                                 int* __restrict__ sums) {
    __shared__ int sh[256];
    int t = threadIdx.x;
    int i = blockIdx.x * 256 + t;
    int v = (i < N_NODES) ? deg[i] : 0;
    sh[t] = v;
    __syncthreads();
    for (int off = 1; off < 256; off <<= 1) {
        int u = (t >= off) ? sh[t - off] : 0;
        __syncthreads();
        sh[t] += u;
        __syncthreads();
    }
    if (i < N_NODES) incl[i] = sh[t];
    if (t == 255) sums[blockIdx.x] = sh[255];
}

__global__ __launch_bounds__(256) void scan_tops(const int* __restrict__ sums,
                                                 int* __restrict__ tops) {
    __shared__ int sh[256];
    int t = threadIdx.x;
    int v = (t < NB256) ? sums[t] : 0;
    sh[t] = v;
    __syncthreads();
    for (int off = 1; off < 256; off <<= 1) {
        int u = (t >= off) ? sh[t - off] : 0;
        __syncthreads();
        sh[t] += u;
        __syncthreads();
    }
    if (t < NB256) tops[t] = sh[t] - v;
}

__global__ void scan_final(const int* __restrict__ deg, const int* __restrict__ incl,
                           const int* __restrict__ tops, int* __restrict__ row_ptr,
                           int* __restrict__ cursor) {
    int i = blockIdx.x * blockDim.x + threadIdx.x;
    if (i < N_NODES) {
        int rp = tops[i >> 8] + incl[i] - deg[i];
        row_ptr[i] = rp;
        cursor[i] = rp;
    }
    if (i == 0) row_ptr[N_NODES] = N_EDGES;
}

__global__ void permute_kernel(const int* __restrict__ srcv, const int* __restrict__ dstv,
                               int* __restrict__ cursor, int* __restrict__ e_src) {
    int e = blockIdx.x * blockDim.x + threadIdx.x;
    if (e < N_EDGES) {
        int pos = atomicAdd(&cursor[dstv[e]], 1);
        e_src[pos] = srcv[e];
    }
}

// ---------------------------------------------------------------------------
// weight prep: all 4 weights W[K][N] fp32 -> Wt[N][K] bf16 in one launch.
// Each is 32768 elems = 128 blocks of 256.
// ---------------------------------------------------------------------------
__global__ void wconv4_kernel(const float* __restrict__ W11, const float* __restrict__ W12,
                              const float* __restrict__ W21, const float* __restrict__ W22,
                              unsigned short* __restrict__ Wt11, unsigned short* __restrict__ Wt12,
                              unsigned short* __restrict__ Wt21, unsigned short* __restrict__ Wt22) {
    int which = blockIdx.x >> 7;              // 0..3
    int idx = (blockIdx.x & 127) * 256 + threadIdx.x;
    const float* W = (which == 0) ? W11 : (which == 1) ? W12 : (which == 2) ? W21 : W22;
    unsigned short* Wt = (which == 0) ? Wt11 : (which == 1) ? Wt12 : (which == 2) ? Wt21 : Wt22;
    int K = (which == 0 || which == 2) ? 128 : 256;
    int N = (which == 0 || which == 2) ? 256 : 128;
    int k = idx / N, n = idx - k * N;
    Wt[n * K + k] = f2b(W[idx]);
}

// x fp32 -> bf16 (8 elems per thread)
__global__ void x2b_kernel(const float* __restrict__ x, unsigned short* __restrict__ xb) {
    int i = blockIdx.x * blockDim.x + threadIdx.x;   // 800000 threads
    if (i >= N_NODES * 128 / 8) return;
    const float4 a = *reinterpret_cast<const float4*>(x + (size_t)i * 8);
    const float4 b = *reinterpret_cast<const float4*>(x + (size_t)i * 8 + 4);
    ushort4 u0, u1;
    u0.x = f2b(a.x); u0.y = f2b(a.y); u0.z = f2b(a.z); u0.w = f2b(a.w);
    u1.x = f2b(b.x); u1.y = f2b(b.y); u1.z = f2b(b.z); u1.w = f2b(b.w);
    *reinterpret_cast<ushort4*>(xb + (size_t)i * 8) = u0;
    *reinterpret_cast<ushort4*>(xb + (size_t)i * 8 + 4) = u1;
}

// ---------------------------------------------------------------------------
// aggregate: agg[i] = x[i] + sum_{e in row i} x[e_src[e]]  — one wave/node.
// Half-wave split: lanes 0-31 process even edges, 32-63 odd edges; each
// half-lane loads ushort4 (8B) covering the full 256B row per half-wave.
// ---------------------------------------------------------------------------
__global__ __launch_bounds__(256) void agg_bf16v(const unsigned short* __restrict__ x,
                                                 const int* __restrict__ row_ptr,
                                                 const int* __restrict__ e_src,
                                                 unsigned short* __restrict__ agg) {
    const int node = (blockIdx.x * 256 + threadIdx.x) >> 6;   // grid sized exactly
    const int lane = threadIdx.x & 63;
    const int half = lane >> 5;
    const int hl = lane & 31;
    const size_t off = (size_t)hl * 4;

    const int beg = row_ptr[node], end = row_ptr[node + 1];
    float4 acc = {0.f, 0.f, 0.f, 0.f};
    if (!half) {
        ushort4 u = *reinterpret_cast<const ushort4*>(x + (size_t)node * 128 + off);
        acc.x = b2f(u.x); acc.y = b2f(u.y); acc.z = b2f(u.z); acc.w = b2f(u.w);
    }
    int e = beg + half;
    for (; e + 2 < end; e += 4) {
        int s0 = e_src[e], s1 = e_src[e + 2];
        ushort4 u0 = *reinterpret_cast<const ushort4*>(x + (size_t)s0 * 128 + off);
        ushort4 u1 = *reinterpret_cast<const ushort4*>(x + (size_t)s1 * 128 + off);
        acc.x += b2f(u0.x) + b2f(u1.x);
        acc.y += b2f(u0.y) + b2f(u1.y);
        acc.z += b2f(u0.z) + b2f(u1.z);
        acc.w += b2f(u0.w) + b2f(u1.w);
    }
    if (e < end) {
        int s = e_src[e];
        ushort4 u = *reinterpret_cast<const ushort4*>(x + (size_t)s * 128 + off);
        acc.x += b2f(u.x);
        acc.y += b2f(u.y);
        acc.z += b2f(u.z);
        acc.w += b2f(u.w);
    }
    // low half += high half (same element range)
    const int srcl = hl + 32;
    acc.x += __shfl(acc.x, srcl);
    acc.y += __shfl(acc.y, srcl);
    acc.z += __shfl(acc.z, srcl);
    acc.w += __shfl(acc.w, srcl);
    if (!half) {
        ushort4 o;
        o.x = f2b(acc.x); o.y = f2b(acc.y); o.z = f2b(acc.z); o.w = f2b(acc.w);
        *reinterpret_cast<ushort4*>(agg + (size_t)node * 128 + off) = o;
    }
}

// ---------------------------------------------------------------------------
// MFMA GEMM: Y[M,N] = act(X[M,K]@W[K,N]+b), X bf16 row-major, Wt bf16 [N][K],
// Y bf16. 128x128 block tile, 4 waves 2x2, 16x16x32 mfma, fp32 accumulate.
// ---------------------------------------------------------------------------
#define LDST 136  // 128 + 8 bf16 pad: 16B-aligned rows, 2-way bank alias only

template <int K, bool RELU>
__global__ __launch_bounds__(256, 2) void mfma_gemm(
    const unsigned short* __restrict__ X, const unsigned short* __restrict__ Wt,
    const float* __restrict__ bias, unsigned short* __restrict__ Y, int M, int N) {
    __shared__ unsigned short A_lds[128 * LDST];
    __shared__ unsigned short B_lds[128 * LDST];

    const int tid = threadIdx.x;
    const int m0 = blockIdx.x * 128;
    const int n0 = blockIdx.y * 128;
    const int lane = tid & 63, wave = tid >> 6;
    const int wm = (wave >> 1) * 64, wn = (wave & 1) * 64;
    const int qm = lane & 15, quad = lane >> 4;

    floatx4 acc[4][4];
#pragma unroll
    for (int mt = 0; mt < 4; ++mt)
#pragma unroll
        for (int nt = 0; nt < 4; ++nt) acc[mt][nt] = {0.f, 0.f, 0.f, 0.f};

    for (int kc = 0; kc < K; kc += 128) {
        if (kc) __syncthreads();
#pragma unroll
        for (int i = 0; i < 8; ++i) {
            int idx = i * 256 + tid;
            int r = idx >> 4;
            int c8 = (idx & 15) << 3;
            uint4 v = {0, 0, 0, 0};
            int row = m0 + r;
            if (row < M) v = *reinterpret_cast<const uint4*>(X + (size_t)row * K + kc + c8);
            *reinterpret_cast<uint4*>(&A_lds[r * LDST + c8]) = v;
        }
#pragma unroll
        for (int i = 0; i < 8; ++i) {
            int idx = i * 256 + tid;
            int r = idx >> 4;
            int c8 = (idx & 15) << 3;
            uint4 v = *reinterpret_cast<const uint4*>(Wt + (size_t)(n0 + r) * K + kc + c8);
            *reinterpret_cast<uint4*>(&B_lds[r * LDST + c8]) = v;
        }
        __syncthreads();

#pragma unroll
        for (int ks = 0; ks < 4; ++ks) {
            short8 a[4], b[4];
            const int kb = ks * 32 + quad * 8;
#pragma unroll
            for (int mt = 0; mt < 4; ++mt)
                a[mt] = *reinterpret_cast<const short8*>(&A_lds[(wm + mt * 16 + qm) * LDST + kb]);
#pragma unroll
            for (int nt = 0; nt < 4; ++nt)
                b[nt] = *reinterpret_cast<const short8*>(&B_lds[(wn + nt * 16 + qm) * LDST + kb]);
#pragma unroll
            for (int mt = 0; mt < 4; ++mt)
#pragma unroll
                for (int nt = 0; nt < 4; ++nt)
                    acc[mt][nt] = __builtin_amdgcn_mfma_f32_16x16x32_bf16(
                        a[mt], b[nt], acc[mt][nt], 0, 0, 0);
        }
    }

#pragma unroll
    for (int nt = 0; nt < 4; ++nt) {
        int col = n0 + wn + nt * 16 + qm;
        float bj = bias[col];
#pragma unroll
        for (int mt = 0; mt < 4; ++mt) {
#pragma unroll
            for (int r = 0; r < 4; ++r) {
                int row = m0 + wm + mt * 16 + quad * 4 + r;
                if (row < M) {
                    float v = acc[mt][nt][r] + bj;
                    if (RELU) v = fmaxf(v, 0.f);
                    Y[(size_t)row * N + col] = f2b(v);
                }
            }
        }
    }
}

// ---------------------------------------------------------------------------
// classifier: out[M,40] = h[M,128] @ Wfc[128,40] + bfc — one row per thread
// ---------------------------------------------------------------------------
__global__ __launch_bounds__(256) void classifier_kernel(
    const unsigned short* __restrict__ h, const float* __restrict__ Wfc,
    const float* __restrict__ bfc, float* __restrict__ out) {
    __shared__ float Ws[128 * 40];
    __shared__ float bs[40];
    for (int i = threadIdx.x; i < 128 * 40; i += 256) Ws[i] = Wfc[i];
    if (threadIdx.x < 40) bs[threadIdx.x] = bfc[threadIdx.x];
    __syncthreads();

    int row = blockIdx.x * 256 + threadIdx.x;
    if (row >= N_NODES) return;
    float acc[40];
#pragma unroll
    for (int j = 0; j < 40; ++j) acc[j] = bs[j];
    const unsigned short* hr = h + (size_t)row * 128;
    for (int k8 = 0; k8 < 128; k8 += 8) {
        ushort4 u0 = *reinterpret_cast<const ushort4*>(hr + k8);
        ushort4 u1 = *reinterpret_cast<const ushort4*>(hr + k8 + 4);
        float xv[8] = {b2f(u0.x), b2f(u0.y), b2f(u0.z), b2f(u0.w),
                       b2f(u1.x), b2f(u1.y), b2f(u1.z), b2f(u1.w)};
#pragma unroll
        for (int kk = 0; kk < 8; ++kk)
#pragma unroll
            for (int j = 0; j < 40; ++j)
                acc[j] = fmaf(xv[kk], Ws[(k8 + kk) * 40 + j], acc[j]);
    }
    float* orow = out + (size_t)row * 40;
#pragma unroll
    for (int j = 0; j < 40; ++j) orow[j] = acc[j];
}

// ---------------------------------------------------------------------------
extern "C" void kernel_launch(void* const* d_in, const int* in_sizes, int n_in,
                              void* d_out, int out_size, void* d_ws, size_t ws_size,
                              hipStream_t stream) {
    const float* x   = (const float*)d_in[0];
    const int*   ei  = (const int*)d_in[1];
    const float* W11 = (const float*)d_in[2];
    const float* b11 = (const float*)d_in[3];
    const float* W12 = (const float*)d_in[4];
    const float* b12 = (const float*)d_in[5];
    const float* W21 = (const float*)d_in[6];
    const float* b21 = (const float*)d_in[7];
    const float* W22 = (const float*)d_in[8];
    const float* b22 = (const float*)d_in[9];
    const float* Wfc = (const float*)d_in[10];
    const float* bfc = (const float*)d_in[11];
    float* out = (float*)d_out;

    const int* srcv = ei;
    const int* dstv = ei + N_EDGES;

    unsigned short* agg  = (unsigned short*)d_ws;               // 50000*128 bf16
    unsigned short* t    = agg + (size_t)N_NODES * 128;         // 50000*256 bf16
    unsigned short* h    = t   + (size_t)N_NODES * 256;         // 50000*128 bf16
    unsigned short* xb   = h   + (size_t)N_NODES * 128;         // 50000*128 bf16
    unsigned short* Wt11 = xb  + (size_t)N_NODES * 128;         // 256*128
    unsigned short* Wt12 = Wt11 + 256 * 128;
    unsigned short* Wt21 = Wt12 + 256 * 128;
    unsigned short* Wt22 = Wt21 + 256 * 128;
    int* deg     = (int*)(Wt22 + 256 * 128);
    int* row_ptr = deg + N_NODES;
    int* cursor  = row_ptr + N_NODES + 4;
    int* e_src   = cursor + N_NODES;
    int* incl    = e_src + N_EDGES;
    int* sums    = incl + NB256 * 256;
    int* tops    = sums + 256;

    // ---- prep: weights + x->bf16 ----
    wconv4_kernel<<<512, 256, 0, stream>>>(W11, W12, W21, W22, Wt11, Wt12, Wt21, Wt22);
    x2b_kernel<<<(N_NODES * 16 + 255) / 256, 256, 0, stream>>>(x, xb);

    // ---- CSR build ----
    zero_kernel<<<NB256, 256, 0, stream>>>(deg, N_NODES);
    hist_kernel<<<(N_EDGES + 255) / 256, 256, 0, stream>>>(dstv, deg);
    scan_part<<<NB256, 256, 0, stream>>>(deg, incl, sums);
    scan_tops<<<1, 256, 0, stream>>>(sums, tops);
    scan_final<<<NB256, 256, 0, stream>>>(deg, incl, tops, row_ptr, cursor);
    permute_kernel<<<(N_EDGES + 255) / 256, 256, 0, stream>>>(srcv, dstv, cursor, e_src);

    const int agg_blocks = N_NODES * 64 / 256;  // 12500, one wave per node

    // ---- layer 1 ----
    agg_bf16v<<<agg_blocks, 256, 0, stream>>>(xb, row_ptr, e_src, agg);
    mfma_gemm<128, true><<<dim3(391, 2), 256, 0, stream>>>(agg, Wt11, b11, t, N_NODES, 256);
    mfma_gemm<256, true><<<dim3(391, 1), 256, 0, stream>>>(t, Wt12, b12, h, N_NODES, 128);
    // ---- layer 2 ----
    agg_bf16v<<<agg_blocks, 256, 0, stream>>>(h, row_ptr, e_src, agg);
    mfma_gemm<128, true><<<dim3(391, 2), 256, 0, stream>>>(agg, Wt21, b21, t, N_NODES, 256);
    mfma_gemm<256, true><<<dim3(391, 1), 256, 0, stream>>>(t, Wt22, b22, h, N_NODES, 128);
    // ---- classifier ----
    classifier_kernel<<<NB256, 256, 0, stream>>>(h, Wfc, bfc, out);
}

// Round 5
// 343.095 us; speedup vs baseline: 9.0961x; 1.0801x over previous
//
#include <hip/hip_runtime.h>

#define N_NODES 50000
#define N_EDGES 800000
#define NB256   ((N_NODES + 255) / 256)   // 196 blocks for node-sized arrays
#define NBUCK   98                        // buckets of 512 nodes (dst >> 9)
#define EPB     8192                      // edges per bucket_scatter block

typedef __attribute__((ext_vector_type(8))) short short8;
typedef __attribute__((ext_vector_type(4))) float floatx4;

__device__ __forceinline__ float b2f(unsigned short u) {
    union { unsigned int i; float f; } v;
    v.i = ((unsigned int)u) << 16;
    return v.f;
}
__device__ __forceinline__ unsigned short f2b(float f) {  // round-nearest-even
    union { float f; unsigned int i; } v;
    v.f = f;
    unsigned int r = v.i + 0x7FFFu + ((v.i >> 16) & 1u);
    return (unsigned short)(r >> 16);
}

// ---------------------------------------------------------------------------
// CSR build
// ---------------------------------------------------------------------------
__global__ void zero_kernel(int* __restrict__ p, int n) {
    int i = blockIdx.x * blockDim.x + threadIdx.x;
    if (i < n) p[i] = 0;
}

__global__ void hist_kernel(const int* __restrict__ dstv, int* __restrict__ deg) {
    int e = blockIdx.x * blockDim.x + threadIdx.x;
    if (e < N_EDGES) atomicAdd(&deg[dstv[e]], 1);
}

__global__ __launch_bounds__(256) void scan_part(const int* __restrict__ deg,
                                                 int* __restrict__ incl,
                                                 int* __restrict__ sums) {
    __shared__ int sh[256];
    int t = threadIdx.x;
    int i = blockIdx.x * 256 + t;
    int v = (i < N_NODES) ? deg[i] : 0;
    sh[t] = v;
    __syncthreads();
    for (int off = 1; off < 256; off <<= 1) {
        int u = (t >= off) ? sh[t - off] : 0;
        __syncthreads();
        sh[t] += u;
        __syncthreads();
    }
    if (i < N_NODES) incl[i] = sh[t];
    if (t == 255) sums[blockIdx.x] = sh[255];
}

__global__ __launch_bounds__(256) void scan_tops(const int* __restrict__ sums,
                                                 int* __restrict__ tops) {
    __shared__ int sh[256];
    int t = threadIdx.x;
    int v = (t < NB256) ? sums[t] : 0;
    sh[t] = v;
    __syncthreads();
    for (int off = 1; off < 256; off <<= 1) {
        int u = (t >= off) ? sh[t - off] : 0;
        __syncthreads();
        sh[t] += u;
        __syncthreads();
    }
    if (t < NB256) tops[t] = sh[t] - v;
}

// row_ptr + per-bucket write cursors (bucket base = row_ptr[b*512])
__global__ void scan_final(const int* __restrict__ deg, const int* __restrict__ incl,
                           const int* __restrict__ tops, int* __restrict__ row_ptr,
                           int* __restrict__ bcur) {
    int i = blockIdx.x * blockDim.x + threadIdx.x;
    if (i < N_NODES) {
        int rp = tops[i >> 8] + incl[i] - deg[i];
        row_ptr[i] = rp;
        if ((i & 511) == 0) bcur[i >> 9] = rp;
    }
    if (i == 0) row_ptr[N_NODES] = N_EDGES;
}

// ---------------------------------------------------------------------------
// Phase B: bucket scatter. Each block claims contiguous per-bucket ranges via
// one global atomic per bucket, then writes packed (src | dstlow<<16) in
// ~84-edge dense runs -> minimal write amplification.
// ---------------------------------------------------------------------------
__global__ __launch_bounds__(256) void bucket_scatter(const int* __restrict__ srcv,
                                                      const int* __restrict__ dstv,
                                                      int* __restrict__ bcur,
                                                      int* __restrict__ tmp) {
    __shared__ int hist[NBUCK];
    __shared__ int base[NBUCK];
    const int tid = threadIdx.x;
    const int e0 = blockIdx.x * EPB;
    for (int i = tid; i < NBUCK; i += 256) hist[i] = 0;
    __syncthreads();
#pragma unroll 4
    for (int j = 0; j < EPB / 256; ++j) {
        int e = e0 + j * 256 + tid;
        if (e < N_EDGES) atomicAdd(&hist[dstv[e] >> 9], 1);
    }
    __syncthreads();
    for (int i = tid; i < NBUCK; i += 256) {
        base[i] = atomicAdd(&bcur[i], hist[i]);
        hist[i] = 0;
    }
    __syncthreads();
#pragma unroll 4
    for (int j = 0; j < EPB / 256; ++j) {
        int e = e0 + j * 256 + tid;
        if (e < N_EDGES) {
            int d = dstv[e];
            int b = d >> 9;
            int r = atomicAdd(&hist[b], 1);
            tmp[base[b] + r] = srcv[e] | ((d & 511) << 16);
        }
    }
}

// ---------------------------------------------------------------------------
// Phase C: per-bucket exact CSR sort in LDS, coalesced write-out.
// Bucket size ~8163 avg (fixed input); buf sized 12288 with huge margin.
// ---------------------------------------------------------------------------
__global__ __launch_bounds__(256) void bucket_sort(const int* __restrict__ row_ptr,
                                                   const int* __restrict__ tmp,
                                                   int* __restrict__ e_src) {
    __shared__ int cur[513];
    __shared__ int buf[12288];
    const int tid = threadIdx.x;
    const int nb = blockIdx.x << 9;
    const int nn = min(512, N_NODES - nb);
    for (int i = tid; i < nn; i += 256) cur[i] = row_ptr[nb + i];
    __syncthreads();
    const int rbase = row_ptr[nb];
    const int rend = row_ptr[nb + nn];
    for (int e = rbase + tid; e < rend; e += 256) {
        int p = tmp[e];
        int dl = (p >> 16) & 511;
        int pos = atomicAdd(&cur[dl], 1) - rbase;
        buf[pos] = p & 0xFFFF;
    }
    __syncthreads();
    const int S = rend - rbase;
    for (int i = tid; i < S; i += 256) e_src[rbase + i] = buf[i];
}

// ---------------------------------------------------------------------------
// Unified prep: 4 weights W[K][N] fp32 -> Wt[N][K] bf16, Wfc -> Wfct[48][128]
// bf16 (zero-padded cols 40..47), x fp32 -> bf16.
// ---------------------------------------------------------------------------
__global__ void prep_kernel(const float* __restrict__ x,
                            const float* __restrict__ W11, const float* __restrict__ W12,
                            const float* __restrict__ W21, const float* __restrict__ W22,
                            const float* __restrict__ Wfc,
                            unsigned short* __restrict__ xb,
                            unsigned short* __restrict__ Wt11, unsigned short* __restrict__ Wt12,
                            unsigned short* __restrict__ Wt21, unsigned short* __restrict__ Wt22,
                            unsigned short* __restrict__ Wfct) {
    int bid = blockIdx.x;
    if (bid < 512) {
        int which = bid >> 7;
        int idx = (bid & 127) * 256 + threadIdx.x;
        const float* W = (which == 0) ? W11 : (which == 1) ? W12 : (which == 2) ? W21 : W22;
        unsigned short* Wt = (which == 0) ? Wt11 : (which == 1) ? Wt12 : (which == 2) ? Wt21 : Wt22;
        int K = (which & 1) ? 256 : 128;
        int N = (which & 1) ? 128 : 256;
        int k = idx / N, n = idx - k * N;
        Wt[n * K + k] = f2b(W[idx]);
    } else if (bid < 536) {
        int idx = (bid - 512) * 256 + threadIdx.x;   // 6144 = 48*128
        int n = idx >> 7, k = idx & 127;
        Wfct[idx] = (n < 40) ? f2b(Wfc[k * 40 + n]) : (unsigned short)0;
    } else {
        int i = (bid - 536) * 256 + threadIdx.x;     // 800000 groups of 8
        if (i < N_NODES * 128 / 8) {
            const float4 a = *reinterpret_cast<const float4*>(x + (size_t)i * 8);
            const float4 b = *reinterpret_cast<const float4*>(x + (size_t)i * 8 + 4);
            ushort4 u0, u1;
            u0.x = f2b(a.x); u0.y = f2b(a.y); u0.z = f2b(a.z); u0.w = f2b(a.w);
            u1.x = f2b(b.x); u1.y = f2b(b.y); u1.z = f2b(b.z); u1.w = f2b(b.w);
            *reinterpret_cast<ushort4*>(xb + (size_t)i * 8) = u0;
            *reinterpret_cast<ushort4*>(xb + (size_t)i * 8 + 4) = u1;
        }
    }
}

// ---------------------------------------------------------------------------
// aggregate: agg[i] = x[i] + sum_{e in row i} x[e_src[e]]  — one wave/node,
// half-wave edge split, ushort4 loads, shfl combine.
// ---------------------------------------------------------------------------
__global__ __launch_bounds__(256) void agg_bf16v(const unsigned short* __restrict__ x,
                                                 const int* __restrict__ row_ptr,
                                                 const int* __restrict__ e_src,
                                                 unsigned short* __restrict__ agg) {
    const int node = (blockIdx.x * 256 + threadIdx.x) >> 6;
    const int lane = threadIdx.x & 63;
    const int half = lane >> 5;
    const int hl = lane & 31;
    const size_t off = (size_t)hl * 4;

    const int beg = row_ptr[node], end = row_ptr[node + 1];
    float4 acc = {0.f, 0.f, 0.f, 0.f};
    if (!half) {
        ushort4 u = *reinterpret_cast<const ushort4*>(x + (size_t)node * 128 + off);
        acc.x = b2f(u.x); acc.y = b2f(u.y); acc.z = b2f(u.z); acc.w = b2f(u.w);
    }
    int e = beg + half;
    for (; e + 2 < end; e += 4) {
        int s0 = e_src[e], s1 = e_src[e + 2];
        ushort4 u0 = *reinterpret_cast<const ushort4*>(x + (size_t)s0 * 128 + off);
        ushort4 u1 = *reinterpret_cast<const ushort4*>(x + (size_t)s1 * 128 + off);
        acc.x += b2f(u0.x) + b2f(u1.x);
        acc.y += b2f(u0.y) + b2f(u1.y);
        acc.z += b2f(u0.z) + b2f(u1.z);
        acc.w += b2f(u0.w) + b2f(u1.w);
    }
    if (e < end) {
        int s = e_src[e];
        ushort4 u = *reinterpret_cast<const ushort4*>(x + (size_t)s * 128 + off);
        acc.x += b2f(u.x);
        acc.y += b2f(u.y);
        acc.z += b2f(u.z);
        acc.w += b2f(u.w);
    }
    const int srcl = hl + 32;
    acc.x += __shfl(acc.x, srcl);
    acc.y += __shfl(acc.y, srcl);
    acc.z += __shfl(acc.z, srcl);
    acc.w += __shfl(acc.w, srcl);
    if (!half) {
        ushort4 o;
        o.x = f2b(acc.x); o.y = f2b(acc.y); o.z = f2b(acc.z); o.w = f2b(acc.w);
        *reinterpret_cast<ushort4*>(agg + (size_t)node * 128 + off) = o;
    }
}

// ---------------------------------------------------------------------------
// MFMA GEMM: Y = act(X@W+b). 128x128 tile, 4 waves 2x2, 16x16x32 bf16 mfma.
// FUSE: instead of writing Y, round-trip the (relu'd) h tile through A_lds
// and compute out = h @ Wfct^T + bfc (classifier) with MFMA, fp32 output.
// ---------------------------------------------------------------------------
#define LDST 136  // 128 + 8 bf16 pad

template <int K, bool RELU, bool FUSE>
__global__ __launch_bounds__(256, 2) void mfma_gemm(
    const unsigned short* __restrict__ X, const unsigned short* __restrict__ Wt,
    const float* __restrict__ bias, unsigned short* __restrict__ Y, int M, int N,
    const unsigned short* __restrict__ Wfct, const float* __restrict__ bfc,
    float* __restrict__ out) {
    __shared__ unsigned short A_lds[128 * LDST];
    __shared__ unsigned short B_lds[128 * LDST];

    const int tid = threadIdx.x;
    const int m0 = blockIdx.x * 128;
    const int n0 = blockIdx.y * 128;
    const int lane = tid & 63, wave = tid >> 6;
    const int wm = (wave >> 1) * 64, wn = (wave & 1) * 64;
    const int qm = lane & 15, quad = lane >> 4;

    floatx4 acc[4][4];
#pragma unroll
    for (int mt = 0; mt < 4; ++mt)
#pragma unroll
        for (int nt = 0; nt < 4; ++nt) acc[mt][nt] = {0.f, 0.f, 0.f, 0.f};

    for (int kc = 0; kc < K; kc += 128) {
        if (kc) __syncthreads();
#pragma unroll
        for (int i = 0; i < 8; ++i) {
            int idx = i * 256 + tid;
            int r = idx >> 4;
            int c8 = (idx & 15) << 3;
            uint4 v = {0, 0, 0, 0};
            int row = m0 + r;
            if (row < M) v = *reinterpret_cast<const uint4*>(X + (size_t)row * K + kc + c8);
            *reinterpret_cast<uint4*>(&A_lds[r * LDST + c8]) = v;
        }
#pragma unroll
        for (int i = 0; i < 8; ++i) {
            int idx = i * 256 + tid;
            int r = idx >> 4;
            int c8 = (idx & 15) << 3;
            uint4 v = *reinterpret_cast<const uint4*>(Wt + (size_t)(n0 + r) * K + kc + c8);
            *reinterpret_cast<uint4*>(&B_lds[r * LDST + c8]) = v;
        }
        __syncthreads();

#pragma unroll
        for (int ks = 0; ks < 4; ++ks) {
            short8 a[4], b[4];
            const int kb = ks * 32 + quad * 8;
#pragma unroll
            for (int mt = 0; mt < 4; ++mt)
                a[mt] = *reinterpret_cast<const short8*>(&A_lds[(wm + mt * 16 + qm) * LDST + kb]);
#pragma unroll
            for (int nt = 0; nt < 4; ++nt)
                b[nt] = *reinterpret_cast<const short8*>(&B_lds[(wn + nt * 16 + qm) * LDST + kb]);
#pragma unroll
            for (int mt = 0; mt < 4; ++mt)
#pragma unroll
                for (int nt = 0; nt < 4; ++nt)
                    acc[mt][nt] = __builtin_amdgcn_mfma_f32_16x16x32_bf16(
                        a[mt], b[nt], acc[mt][nt], 0, 0, 0);
        }
    }

    if (FUSE) __syncthreads();  // all waves done reading A_lds before reuse

    // epilogue: C/D layout col=lane&15, row=quad*4+reg
#pragma unroll
    for (int nt = 0; nt < 4; ++nt) {
        int col = n0 + wn + nt * 16 + qm;
        float bj = bias[col];
#pragma unroll
        for (int mt = 0; mt < 4; ++mt) {
#pragma unroll
            for (int r = 0; r < 4; ++r) {
                int row = m0 + wm + mt * 16 + quad * 4 + r;
                float v = acc[mt][nt][r] + bj;
                if (RELU) v = fmaxf(v, 0.f);
                if (FUSE) {
                    // stash h tile in LDS (local coords), skip global write
                    A_lds[(wm + mt * 16 + quad * 4 + r) * LDST + (wn + nt * 16 + qm)] = f2b(v);
                } else if (row < M) {
                    Y[(size_t)row * N + col] = f2b(v);
                }
            }
        }
    }

    if (FUSE) {
        __syncthreads();
        // classifier: out[128,40] = h_tile(128x128) @ Wfct^T(128x48) + bfc
        // wave w handles rows 32w..32w+31 (2 m-tiles), 3 n-tiles of 16 (48 cols)
        floatx4 cacc[2][3];
#pragma unroll
        for (int mt = 0; mt < 2; ++mt)
#pragma unroll
            for (int nt = 0; nt < 3; ++nt) cacc[mt][nt] = {0.f, 0.f, 0.f, 0.f};
#pragma unroll
        for (int ks = 0; ks < 4; ++ks) {
            const int kb = ks * 32 + quad * 8;
            short8 a0 = *reinterpret_cast<const short8*>(&A_lds[(wave * 32 + qm) * LDST + kb]);
            short8 a1 = *reinterpret_cast<const short8*>(&A_lds[(wave * 32 + 16 + qm) * LDST + kb]);
            short8 bf[3];
#pragma unroll
            for (int nt = 0; nt < 3; ++nt)
                bf[nt] = *reinterpret_cast<const short8*>(Wfct + (nt * 16 + qm) * 128 + kb);
#pragma unroll
            for (int nt = 0; nt < 3; ++nt) {
                cacc[0][nt] = __builtin_amdgcn_mfma_f32_16x16x32_bf16(a0, bf[nt], cacc[0][nt], 0, 0, 0);
                cacc[1][nt] = __builtin_amdgcn_mfma_f32_16x16x32_bf16(a1, bf[nt], cacc[1][nt], 0, 0, 0);
            }
        }
#pragma unroll
        for (int nt = 0; nt < 3; ++nt) {
            int col = nt * 16 + qm;
            if (col < 40) {
                float bj = bfc[col];
#pragma unroll
                for (int mt = 0; mt < 2; ++mt) {
#pragma unroll
                    for (int r = 0; r < 4; ++r) {
                        int row = m0 + wave * 32 + mt * 16 + quad * 4 + r;
                        if (row < M) out[(size_t)row * 40 + col] = cacc[mt][nt][r] + bj;
                    }
                }
            }
        }
    }
}

// ---------------------------------------------------------------------------
extern "C" void kernel_launch(void* const* d_in, const int* in_sizes, int n_in,
                              void* d_out, int out_size, void* d_ws, size_t ws_size,
                              hipStream_t stream) {
    const float* x   = (const float*)d_in[0];
    const int*   ei  = (const int*)d_in[1];
    const float* W11 = (const float*)d_in[2];
    const float* b11 = (const float*)d_in[3];
    const float* W12 = (const float*)d_in[4];
    const float* b12 = (const float*)d_in[5];
    const float* W21 = (const float*)d_in[6];
    const float* b21 = (const float*)d_in[7];
    const float* W22 = (const float*)d_in[8];
    const float* b22 = (const float*)d_in[9];
    const float* Wfc = (const float*)d_in[10];
    const float* bfc = (const float*)d_in[11];
    float* out = (float*)d_out;

    const int* srcv = ei;
    const int* dstv = ei + N_EDGES;

    unsigned short* agg  = (unsigned short*)d_ws;               // 50000*128 bf16
    unsigned short* t    = agg + (size_t)N_NODES * 128;         // 50000*256 bf16
    unsigned short* h    = t   + (size_t)N_NODES * 256;         // 50000*128 bf16
    unsigned short* xb   = h   + (size_t)N_NODES * 128;         // 50000*128 bf16
    unsigned short* Wt11 = xb  + (size_t)N_NODES * 128;
    unsigned short* Wt12 = Wt11 + 256 * 128;
    unsigned short* Wt21 = Wt12 + 256 * 128;
    unsigned short* Wt22 = Wt21 + 256 * 128;
    unsigned short* Wfct = Wt22 + 256 * 128;                    // 48*128
    int* deg     = (int*)(Wfct + 48 * 128);
    int* row_ptr = deg + N_NODES;                               // N+1
    int* bcur    = row_ptr + N_NODES + 4;                       // 98
    int* e_src   = bcur + 128;
    int* tmp     = e_src + N_EDGES;
    int* incl    = tmp + N_EDGES;
    int* sums    = incl + NB256 * 256;
    int* tops    = sums + 256;

    // ---- prep (weights + Wfc pad/transpose + x->bf16) ----
    prep_kernel<<<3661, 256, 0, stream>>>(x, W11, W12, W21, W22, Wfc,
                                          xb, Wt11, Wt12, Wt21, Wt22, Wfct);

    // ---- CSR build ----
    zero_kernel<<<NB256, 256, 0, stream>>>(deg, N_NODES);
    hist_kernel<<<(N_EDGES + 255) / 256, 256, 0, stream>>>(dstv, deg);
    scan_part<<<NB256, 256, 0, stream>>>(deg, incl, sums);
    scan_tops<<<1, 256, 0, stream>>>(sums, tops);
    scan_final<<<NB256, 256, 0, stream>>>(deg, incl, tops, row_ptr, bcur);
    bucket_scatter<<<(N_EDGES + EPB - 1) / EPB, 256, 0, stream>>>(srcv, dstv, bcur, tmp);
    bucket_sort<<<NBUCK, 256, 0, stream>>>(row_ptr, tmp, e_src);

    const int agg_blocks = N_NODES * 64 / 256;  // 12500, one wave per node

    // ---- layer 1 ----
    agg_bf16v<<<agg_blocks, 256, 0, stream>>>(xb, row_ptr, e_src, agg);
    mfma_gemm<128, true, false><<<dim3(391, 2), 256, 0, stream>>>(
        agg, Wt11, b11, t, N_NODES, 256, nullptr, nullptr, nullptr);
    mfma_gemm<256, true, false><<<dim3(391, 1), 256, 0, stream>>>(
        t, Wt12, b12, h, N_NODES, 128, nullptr, nullptr, nullptr);
    // ---- layer 2 (classifier fused into final GEMM) ----
    agg_bf16v<<<agg_blocks, 256, 0, stream>>>(h, row_ptr, e_src, agg);
    mfma_gemm<128, true, false><<<dim3(391, 2), 256, 0, stream>>>(
        agg, Wt21, b21, t, N_NODES, 256, nullptr, nullptr, nullptr);
    mfma_gemm<256, true, true><<<dim3(391, 1), 256, 0, stream>>>(
        t, Wt22, b22, nullptr, N_NODES, 128, Wfct, bfc, out);
}

// Round 6
// 302.919 us; speedup vs baseline: 10.3026x; 1.1326x over previous
//
#include <hip/hip_runtime.h>

#define N_NODES 50000
#define N_EDGES 800000
#define NB256   ((N_NODES + 255) / 256)   // 196 blocks for node-sized arrays
#define NBUCK   98                        // buckets of 512 nodes (dst >> 9)
#define EPB     8192                      // edges per bucket_scatter block

typedef __attribute__((ext_vector_type(8))) short short8;
typedef __attribute__((ext_vector_type(4))) float floatx4;

__device__ __forceinline__ float b2f(unsigned short u) {
    union { unsigned int i; float f; } v;
    v.i = ((unsigned int)u) << 16;
    return v.f;
}
__device__ __forceinline__ unsigned short f2b(float f) {  // round-nearest-even
    union { float f; unsigned int i; } v;
    v.f = f;
    unsigned int r = v.i + 0x7FFFu + ((v.i >> 16) & 1u);
    return (unsigned short)(r >> 16);
}

// ---------------------------------------------------------------------------
// CSR build
// ---------------------------------------------------------------------------
__global__ void hist_kernel(const int* __restrict__ dstv, int* __restrict__ deg) {
    int e = blockIdx.x * blockDim.x + threadIdx.x;
    if (e < N_EDGES) atomicAdd(&deg[dstv[e]], 1);
}

__global__ __launch_bounds__(256) void scan_part(const int* __restrict__ deg,
                                                 int* __restrict__ incl,
                                                 int* __restrict__ sums) {
    __shared__ int sh[256];
    int t = threadIdx.x;
    int i = blockIdx.x * 256 + t;
    int v = (i < N_NODES) ? deg[i] : 0;
    sh[t] = v;
    __syncthreads();
    for (int off = 1; off < 256; off <<= 1) {
        int u = (t >= off) ? sh[t - off] : 0;
        __syncthreads();
        sh[t] += u;
        __syncthreads();
    }
    if (i < N_NODES) incl[i] = sh[t];
    if (t == 255) sums[blockIdx.x] = sh[255];
}

__global__ __launch_bounds__(256) void scan_tops(const int* __restrict__ sums,
                                                 int* __restrict__ tops) {
    __shared__ int sh[256];
    int t = threadIdx.x;
    int v = (t < NB256) ? sums[t] : 0;
    sh[t] = v;
    __syncthreads();
    for (int off = 1; off < 256; off <<= 1) {
        int u = (t >= off) ? sh[t - off] : 0;
        __syncthreads();
        sh[t] += u;
        __syncthreads();
    }
    if (t < NB256) tops[t] = sh[t] - v;
}

__global__ void scan_final(const int* __restrict__ deg, const int* __restrict__ incl,
                           const int* __restrict__ tops, int* __restrict__ row_ptr,
                           int* __restrict__ bcur) {
    int i = blockIdx.x * blockDim.x + threadIdx.x;
    if (i < N_NODES) {
        int rp = tops[i >> 8] + incl[i] - deg[i];
        row_ptr[i] = rp;
        if ((i & 511) == 0) bcur[i >> 9] = rp;
    }
    if (i == 0) row_ptr[N_NODES] = N_EDGES;
}

__global__ __launch_bounds__(256) void bucket_scatter(const int* __restrict__ srcv,
                                                      const int* __restrict__ dstv,
                                                      int* __restrict__ bcur,
                                                      int* __restrict__ tmp) {
    __shared__ int hist[NBUCK];
    __shared__ int base[NBUCK];
    const int tid = threadIdx.x;
    const int e0 = blockIdx.x * EPB;
    for (int i = tid; i < NBUCK; i += 256) hist[i] = 0;
    __syncthreads();
#pragma unroll 4
    for (int j = 0; j < EPB / 256; ++j) {
        int e = e0 + j * 256 + tid;
        if (e < N_EDGES) atomicAdd(&hist[dstv[e] >> 9], 1);
    }
    __syncthreads();
    for (int i = tid; i < NBUCK; i += 256) {
        base[i] = atomicAdd(&bcur[i], hist[i]);
        hist[i] = 0;
    }
    __syncthreads();
#pragma unroll 4
    for (int j = 0; j < EPB / 256; ++j) {
        int e = e0 + j * 256 + tid;
        if (e < N_EDGES) {
            int d = dstv[e];
            int b = d >> 9;
            int r = atomicAdd(&hist[b], 1);
            tmp[base[b] + r] = srcv[e] | ((d & 511) << 16);
        }
    }
}

__global__ __launch_bounds__(256) void bucket_sort(const int* __restrict__ row_ptr,
                                                   const int* __restrict__ tmp,
                                                   int* __restrict__ e_src) {
    __shared__ int cur[513];
    __shared__ int buf[12288];
    const int tid = threadIdx.x;
    const int nb = blockIdx.x << 9;
    const int nn = min(512, N_NODES - nb);
    for (int i = tid; i < nn; i += 256) cur[i] = row_ptr[nb + i];
    __syncthreads();
    const int rbase = row_ptr[nb];
    const int rend = row_ptr[nb + nn];
    for (int e = rbase + tid; e < rend; e += 256) {
        int p = tmp[e];
        int dl = (p >> 16) & 511;
        int pos = atomicAdd(&cur[dl], 1) - rbase;
        buf[pos] = p & 0xFFFF;
    }
    __syncthreads();
    const int S = rend - rbase;
    for (int i = tid; i < S; i += 256) e_src[rbase + i] = buf[i];
}

// ---------------------------------------------------------------------------
// Unified prep: 4 weights -> Wt bf16, Wfc -> Wfct[48][128] bf16 (padded),
// x -> bf16, deg -> 0.
// ---------------------------------------------------------------------------
__global__ void prep_kernel(const float* __restrict__ x,
                            const float* __restrict__ W11, const float* __restrict__ W12,
                            const float* __restrict__ W21, const float* __restrict__ W22,
                            const float* __restrict__ Wfc,
                            unsigned short* __restrict__ xb,
                            unsigned short* __restrict__ Wt11, unsigned short* __restrict__ Wt12,
                            unsigned short* __restrict__ Wt21, unsigned short* __restrict__ Wt22,
                            unsigned short* __restrict__ Wfct,
                            int* __restrict__ deg) {
    int bid = blockIdx.x;
    if (bid < 512) {
        int which = bid >> 7;
        int idx = (bid & 127) * 256 + threadIdx.x;
        const float* W = (which == 0) ? W11 : (which == 1) ? W12 : (which == 2) ? W21 : W22;
        unsigned short* Wt = (which == 0) ? Wt11 : (which == 1) ? Wt12 : (which == 2) ? Wt21 : Wt22;
        int K = (which & 1) ? 256 : 128;
        int N = (which & 1) ? 128 : 256;
        int k = idx / N, n = idx - k * N;
        Wt[n * K + k] = f2b(W[idx]);
    } else if (bid < 536) {
        int idx = (bid - 512) * 256 + threadIdx.x;   // 6144 = 48*128
        int n = idx >> 7, k = idx & 127;
        Wfct[idx] = (n < 40) ? f2b(Wfc[k * 40 + n]) : (unsigned short)0;
    } else if (bid < 3661) {
        int i = (bid - 536) * 256 + threadIdx.x;     // 800000 groups of 8
        const float4 a = *reinterpret_cast<const float4*>(x + (size_t)i * 8);
        const float4 b = *reinterpret_cast<const float4*>(x + (size_t)i * 8 + 4);
        ushort4 u0, u1;
        u0.x = f2b(a.x); u0.y = f2b(a.y); u0.z = f2b(a.z); u0.w = f2b(a.w);
        u1.x = f2b(b.x); u1.y = f2b(b.y); u1.z = f2b(b.z); u1.w = f2b(b.w);
        *reinterpret_cast<ushort4*>(xb + (size_t)i * 8) = u0;
        *reinterpret_cast<ushort4*>(xb + (size_t)i * 8 + 4) = u1;
    } else {
        int i = (bid - 3661) * 256 + threadIdx.x;
        if (i < N_NODES) deg[i] = 0;
    }
}

// ---------------------------------------------------------------------------
// aggregate: agg[i] = x[i] + sum_{e in row i} x[e_src[e]]  — one wave/node,
// half-wave edge split, ushort4 loads, shfl combine.
// ---------------------------------------------------------------------------
__global__ __launch_bounds__(256) void agg_bf16v(const unsigned short* __restrict__ x,
                                                 const int* __restrict__ row_ptr,
                                                 const int* __restrict__ e_src,
                                                 unsigned short* __restrict__ agg) {
    const int node = (blockIdx.x * 256 + threadIdx.x) >> 6;
    const int lane = threadIdx.x & 63;
    const int half = lane >> 5;
    const int hl = lane & 31;
    const size_t off = (size_t)hl * 4;

    const int beg = row_ptr[node], end = row_ptr[node + 1];
    float4 acc = {0.f, 0.f, 0.f, 0.f};
    if (!half) {
        ushort4 u = *reinterpret_cast<const ushort4*>(x + (size_t)node * 128 + off);
        acc.x = b2f(u.x); acc.y = b2f(u.y); acc.z = b2f(u.z); acc.w = b2f(u.w);
    }
    int e = beg + half;
    for (; e + 2 < end; e += 4) {
        int s0 = e_src[e], s1 = e_src[e + 2];
        ushort4 u0 = *reinterpret_cast<const ushort4*>(x + (size_t)s0 * 128 + off);
        ushort4 u1 = *reinterpret_cast<const ushort4*>(x + (size_t)s1 * 128 + off);
        acc.x += b2f(u0.x) + b2f(u1.x);
        acc.y += b2f(u0.y) + b2f(u1.y);
        acc.z += b2f(u0.z) + b2f(u1.z);
        acc.w += b2f(u0.w) + b2f(u1.w);
    }
    if (e < end) {
        int s = e_src[e];
        ushort4 u = *reinterpret_cast<const ushort4*>(x + (size_t)s * 128 + off);
        acc.x += b2f(u.x);
        acc.y += b2f(u.y);
        acc.z += b2f(u.z);
        acc.w += b2f(u.w);
    }
    const int srcl = hl + 32;
    acc.x += __shfl(acc.x, srcl);
    acc.y += __shfl(acc.y, srcl);
    acc.z += __shfl(acc.z, srcl);
    acc.w += __shfl(acc.w, srcl);
    if (!half) {
        ushort4 o;
        o.x = f2b(acc.x); o.y = f2b(acc.y); o.z = f2b(acc.z); o.w = f2b(acc.w);
        *reinterpret_cast<ushort4*>(agg + (size_t)node * 128 + off) = o;
    }
}

// ---------------------------------------------------------------------------
// Fused MLP: Y = relu(relu(X@W1+b1)@W2+b2) for a 64-row strip, t kept in LDS.
// FUSE variant additionally computes out = h @ Wfct^T + bfc (classifier)
// chunk-by-chunk (h never touches global memory).
// LDS layout (bytes):
//   [0,     17408): A[64][136]      | stage2: B2q[32][264] (16896)
//   [17408, 52224): B1h[128][136]   | stage2: T[64][264]   (33792)
//   [52224, 57344): Hc[64][40]      (FUSE only)
// ---------------------------------------------------------------------------
template <bool FUSE>
__global__ __launch_bounds__(256, 2) void mlp_fused(
    const unsigned short* __restrict__ X, const unsigned short* __restrict__ Wt1,
    const float* __restrict__ b1, const unsigned short* __restrict__ Wt2,
    const float* __restrict__ b2, unsigned short* __restrict__ Y,
    const unsigned short* __restrict__ Wfct, const float* __restrict__ bfc,
    float* __restrict__ out, int M) {
    __shared__ __align__(16) char smem[FUSE ? 57344 : 52224];
    unsigned short* A   = (unsigned short*)smem;             // [64][136]
    unsigned short* B2q = (unsigned short*)smem;             // [32][264]
    unsigned short* B1h = (unsigned short*)(smem + 17408);   // [128][136]
    unsigned short* T   = (unsigned short*)(smem + 17408);   // [64][264]
    unsigned short* Hc  = (unsigned short*)(smem + 52224);   // [64][40]

    const int tid = threadIdx.x;
    const int m0 = blockIdx.x * 64;
    const int lane = tid & 63, w = tid >> 6;
    const int qm = lane & 15, quad = lane >> 4;

    // ---- load A (64 x 128 bf16) ----
#pragma unroll
    for (int j = 0; j < 4; ++j) {
        int i = j * 256 + tid;
        int r = i >> 4, c8 = (i & 15) << 3;
        uint4 v = {0, 0, 0, 0};
        if (m0 + r < M) v = *reinterpret_cast<const uint4*>(X + (size_t)(m0 + r) * 128 + c8);
        *reinterpret_cast<uint4*>(&A[r * 136 + c8]) = v;
    }

    // ---- stage 1: t[64][256] = relu(A @ W1 + b1), acc in VGPRs ----
    floatx4 acc1[2][4][2];
#pragma unroll
    for (int c = 0; c < 2; ++c)
#pragma unroll
        for (int mt = 0; mt < 4; ++mt)
#pragma unroll
            for (int nt = 0; nt < 2; ++nt) acc1[c][mt][nt] = {0.f, 0.f, 0.f, 0.f};

    for (int c = 0; c < 2; ++c) {
#pragma unroll
        for (int j = 0; j < 8; ++j) {
            int i = j * 256 + tid;
            int r = i >> 4, c8 = (i & 15) << 3;
            *reinterpret_cast<uint4*>(&B1h[r * 136 + c8]) =
                *reinterpret_cast<const uint4*>(Wt1 + (size_t)(c * 128 + r) * 128 + c8);
        }
        __syncthreads();
#pragma unroll
        for (int ks = 0; ks < 4; ++ks) {
            const int kb = ks * 32 + quad * 8;
            short8 a[4], b[2];
#pragma unroll
            for (int mt = 0; mt < 4; ++mt)
                a[mt] = *reinterpret_cast<const short8*>(&A[(mt * 16 + qm) * 136 + kb]);
#pragma unroll
            for (int nt = 0; nt < 2; ++nt)
                b[nt] = *reinterpret_cast<const short8*>(&B1h[(w * 32 + nt * 16 + qm) * 136 + kb]);
#pragma unroll
            for (int mt = 0; mt < 4; ++mt)
#pragma unroll
                for (int nt = 0; nt < 2; ++nt)
                    acc1[c][mt][nt] = __builtin_amdgcn_mfma_f32_16x16x32_bf16(
                        a[mt], b[nt], acc1[c][mt][nt], 0, 0, 0);
        }
        __syncthreads();
    }

    // ---- epilogue 1: T (bf16, LDS) = relu(acc1 + b1) ----
#pragma unroll
    for (int c = 0; c < 2; ++c) {
#pragma unroll
        for (int nt = 0; nt < 2; ++nt) {
            const int jcol = c * 128 + w * 32 + nt * 16 + qm;
            const float bj = b1[jcol];
#pragma unroll
            for (int mt = 0; mt < 4; ++mt)
#pragma unroll
                for (int r = 0; r < 4; ++r)
                    T[(mt * 16 + quad * 4 + r) * 264 + jcol] =
                        f2b(fmaxf(acc1[c][mt][nt][r] + bj, 0.f));
        }
    }

    // ---- stage 2: h = relu(T @ W2 + b2), W2 streamed in 4x32-row chunks ----
    floatx4 cacc[3];
#pragma unroll
    for (int nt = 0; nt < 3; ++nt) cacc[nt] = {0.f, 0.f, 0.f, 0.f};

    for (int c2 = 0; c2 < 4; ++c2) {
#pragma unroll
        for (int j = 0; j < 4; ++j) {
            int i = j * 256 + tid;
            int r = i >> 5, c8 = (i & 31) << 3;
            *reinterpret_cast<uint4*>(&B2q[r * 264 + c8]) =
                *reinterpret_cast<const uint4*>(Wt2 + (size_t)(c2 * 32 + r) * 256 + c8);
        }
        __syncthreads();

        floatx4 acc2[2];
        acc2[0] = {0.f, 0.f, 0.f, 0.f};
        acc2[1] = {0.f, 0.f, 0.f, 0.f};
#pragma unroll
        for (int ks = 0; ks < 8; ++ks) {
            const int kb = ks * 32 + quad * 8;
            short8 t0 = *reinterpret_cast<const short8*>(&T[((w & 1) * 32 + qm) * 264 + kb]);
            short8 t1 = *reinterpret_cast<const short8*>(&T[((w & 1) * 32 + 16 + qm) * 264 + kb]);
            short8 bb = *reinterpret_cast<const short8*>(&B2q[((w >> 1) * 16 + qm) * 264 + kb]);
            acc2[0] = __builtin_amdgcn_mfma_f32_16x16x32_bf16(t0, bb, acc2[0], 0, 0, 0);
            acc2[1] = __builtin_amdgcn_mfma_f32_16x16x32_bf16(t1, bb, acc2[1], 0, 0, 0);
        }

        const int ncol = c2 * 32 + (w >> 1) * 16 + qm;   // global h col
        const float bj = b2[ncol];
        if (!FUSE) {
#pragma unroll
            for (int mt2 = 0; mt2 < 2; ++mt2)
#pragma unroll
                for (int r = 0; r < 4; ++r) {
                    int row = m0 + (w & 1) * 32 + mt2 * 16 + quad * 4 + r;
                    if (row < M)
                        Y[(size_t)row * 128 + ncol] = f2b(fmaxf(acc2[mt2][r] + bj, 0.f));
                }
            __syncthreads();
        } else {
            const int lcol = (w >> 1) * 16 + qm;
#pragma unroll
            for (int mt2 = 0; mt2 < 2; ++mt2)
#pragma unroll
                for (int r = 0; r < 4; ++r)
                    Hc[((w & 1) * 32 + mt2 * 16 + quad * 4 + r) * 40 + lcol] =
                        f2b(fmaxf(acc2[mt2][r] + bj, 0.f));
            __syncthreads();
            // classifier partial: out += h[:, c2*32:+32] @ Wfct[:, c2*32:+32]^T
            short8 hf = *reinterpret_cast<const short8*>(&Hc[(w * 16 + qm) * 40 + quad * 8]);
#pragma unroll
            for (int nt = 0; nt < 3; ++nt) {
                short8 bf = *reinterpret_cast<const short8*>(
                    Wfct + (nt * 16 + qm) * 128 + c2 * 32 + quad * 8);
                cacc[nt] = __builtin_amdgcn_mfma_f32_16x16x32_bf16(hf, bf, cacc[nt], 0, 0, 0);
            }
            __syncthreads();
        }
    }

    if (FUSE) {
#pragma unroll
        for (int nt = 0; nt < 3; ++nt) {
            int col = nt * 16 + qm;
            if (col < 40) {
                const float bj = bfc[col];
#pragma unroll
                for (int r = 0; r < 4; ++r) {
                    int row = m0 + w * 16 + quad * 4 + r;
                    if (row < M) out[(size_t)row * 40 + col] = cacc[nt][r] + bj;
                }
            }
        }
    }
}

// ---------------------------------------------------------------------------
extern "C" void kernel_launch(void* const* d_in, const int* in_sizes, int n_in,
                              void* d_out, int out_size, void* d_ws, size_t ws_size,
                              hipStream_t stream) {
    const float* x   = (const float*)d_in[0];
    const int*   ei  = (const int*)d_in[1];
    const float* W11 = (const float*)d_in[2];
    const float* b11 = (const float*)d_in[3];
    const float* W12 = (const float*)d_in[4];
    const float* b12 = (const float*)d_in[5];
    const float* W21 = (const float*)d_in[6];
    const float* b21 = (const float*)d_in[7];
    const float* W22 = (const float*)d_in[8];
    const float* b22 = (const float*)d_in[9];
    const float* Wfc = (const float*)d_in[10];
    const float* bfc = (const float*)d_in[11];
    float* out = (float*)d_out;

    const int* srcv = ei;
    const int* dstv = ei + N_EDGES;

    unsigned short* agg  = (unsigned short*)d_ws;               // 50000*128 bf16
    unsigned short* h    = agg + (size_t)N_NODES * 128;         // 50000*128 bf16
    unsigned short* xb   = h   + (size_t)N_NODES * 128;         // 50000*128 bf16
    unsigned short* Wt11 = xb  + (size_t)N_NODES * 128;
    unsigned short* Wt12 = Wt11 + 256 * 128;
    unsigned short* Wt21 = Wt12 + 256 * 128;
    unsigned short* Wt22 = Wt21 + 256 * 128;
    unsigned short* Wfct = Wt22 + 256 * 128;                    // 48*128
    int* deg     = (int*)(Wfct + 48 * 128);
    int* row_ptr = deg + N_NODES;                               // N+1
    int* bcur    = row_ptr + N_NODES + 4;                       // 98
    int* e_src   = bcur + 128;
    int* tmp     = e_src + N_EDGES;
    int* incl    = tmp + N_EDGES;
    int* sums    = incl + NB256 * 256;
    int* tops    = sums + 256;

    // ---- prep (weights + Wfc + x->bf16 + deg=0) ----
    prep_kernel<<<3661 + NB256, 256, 0, stream>>>(x, W11, W12, W21, W22, Wfc,
                                                  xb, Wt11, Wt12, Wt21, Wt22, Wfct, deg);

    // ---- CSR build ----
    hist_kernel<<<(N_EDGES + 255) / 256, 256, 0, stream>>>(dstv, deg);
    scan_part<<<NB256, 256, 0, stream>>>(deg, incl, sums);
    scan_tops<<<1, 256, 0, stream>>>(sums, tops);
    scan_final<<<NB256, 256, 0, stream>>>(deg, incl, tops, row_ptr, bcur);
    bucket_scatter<<<(N_EDGES + EPB - 1) / EPB, 256, 0, stream>>>(srcv, dstv, bcur, tmp);
    bucket_sort<<<NBUCK, 256, 0, stream>>>(row_ptr, tmp, e_src);

    const int agg_blocks = N_NODES * 64 / 256;        // 12500, one wave per node
    const int mlp_blocks = (N_NODES + 63) / 64;       // 782

    // ---- layer 1 ----
    agg_bf16v<<<agg_blocks, 256, 0, stream>>>(xb, row_ptr, e_src, agg);
    mlp_fused<false><<<mlp_blocks, 256, 0, stream>>>(
        agg, Wt11, b11, Wt12, b12, h, nullptr, nullptr, nullptr, N_NODES);
    // ---- layer 2 + classifier ----
    agg_bf16v<<<agg_blocks, 256, 0, stream>>>(h, row_ptr, e_src, agg);
    mlp_fused<true><<<mlp_blocks, 256, 0, stream>>>(
        agg, Wt21, b21, Wt22, b22, nullptr, Wfct, bfc, out, N_NODES);
}